// Round 2
// baseline (2388.121 us; speedup 1.0000x reference)
//
#include <hip/hip_runtime.h>

#define EPS 1e-5f

// ---------------- kernels ----------------

__global__ void k_deg(const int* __restrict__ col, const float* __restrict__ w,
                      float* __restrict__ deg, int E) {
    int e = blockIdx.x * blockDim.x + threadIdx.x;
    if (e < E) atomicAdd(&deg[col[e]], w[e]);
}

__global__ void k_dinv(const float* __restrict__ deg, float* __restrict__ dinv, int N) {
    int i = blockIdx.x * blockDim.x + threadIdx.x;
    if (i < N) {
        float d = deg[i] + 1.0f;   // + self-loop weight 1
        dinv[i] = rsqrtf(d);       // always > 0
    }
}

__global__ void k_norm(const int* __restrict__ row, const int* __restrict__ col,
                       const float* __restrict__ w, const float* __restrict__ dinv,
                       float* __restrict__ norm, int E) {
    int e = blockIdx.x * blockDim.x + threadIdx.x;
    if (e < E) norm[e] = dinv[row[e]] * w[e] * dinv[col[e]];
}

// Y[i,j] = (bias?bias[j]:0) + sum_k X[i,k] * W[k,j]   (optionally ReLU)
__global__ void k_gemm(const float* __restrict__ X, const float* __restrict__ W,
                       const float* __restrict__ bias, float* __restrict__ Y,
                       int N, int K, int M, int applyRelu) {
    int t = blockIdx.x * blockDim.x + threadIdx.x;
    if (t >= N * M) return;
    int i = t / M;
    int j = t - i * M;
    const float* xr = X + (long long)i * K;
    float acc = bias ? bias[j] : 0.0f;
#pragma unroll 4
    for (int k = 0; k < K; ++k) acc += xr[k] * W[k * M + j];
    if (applyRelu) acc = fmaxf(acc, 0.0f);
    Y[t] = acc;
}

// AGG[col[e], f] += norm[e] * H[row[e], f]
__global__ void k_scatter(const int* __restrict__ row, const int* __restrict__ col,
                          const float* __restrict__ norm, const float* __restrict__ H,
                          float* __restrict__ AGG, int E, int M) {
    int t = blockIdx.x * blockDim.x + threadIdx.x;
    if (t >= E * M) return;
    int e = t / M;
    int f = t - e * M;
    float v = norm[e] * H[(long long)row[e] * M + f];
    atomicAdd(&AGG[(long long)col[e] * M + f], v);
}

// in-place: A[i,f] = maybe_relu(A[i,f] + dinv[i]^2 * Hpre[i,f] + b[f])
__global__ void k_finish(float* __restrict__ A, const float* __restrict__ Hpre,
                         const float* __restrict__ dinv, const float* __restrict__ b,
                         int N, int M, int reluBefore) {
    int t = blockIdx.x * blockDim.x + threadIdx.x;
    if (t >= N * M) return;
    int i = t / M;
    int f = t - i * M;
    float di = dinv[i];
    float v = A[t] + di * di * Hpre[t] + b[f];
    if (reluBefore) v = fmaxf(v, 0.0f);
    A[t] = v;
}

// column sums / sums-of-squares (for BN stats)
__global__ void k_colsum(const float* __restrict__ Y, float* __restrict__ sums,
                         float* __restrict__ sumsq, int N, int M) {
    int f = threadIdx.x & (M - 1);      // M is a power of two
    int rsub = threadIdx.x / M;
    int R = blockDim.x / M;
    int rowsPerBlock = (N + gridDim.x - 1) / gridDim.x;
    int r0 = blockIdx.x * rowsPerBlock;
    int r1 = min(N, r0 + rowsPerBlock);
    float s = 0.0f, s2 = 0.0f;
    for (int i = r0 + rsub; i < r1; i += R) {
        float v = Y[(long long)i * M + f];
        s += v;
        s2 += v * v;
    }
    atomicAdd(&sums[f], s);
    atomicAdd(&sumsq[f], s2);
}

// OUT[i,f] = maybe_relu( g[f]*(Y[i,f]-mean[f])*rsqrt(var[f]+eps) + be[f] )
__global__ void k_bn(const float* __restrict__ Y, const float* __restrict__ sums,
                     const float* __restrict__ sumsq, const float* __restrict__ g,
                     const float* __restrict__ be, float* __restrict__ OUT,
                     int N, int M, int reluAfter) {
    int t = blockIdx.x * blockDim.x + threadIdx.x;
    if (t >= N * M) return;
    int i = t / M;
    int f = t - i * M;
    float invN = 1.0f / (float)N;
    float mean = sums[f] * invN;
    float var = sumsq[f] * invN - mean * mean;
    float v = g[f] * (Y[t] - mean) * rsqrtf(var + EPS) + be[f];
    if (reluAfter) v = fmaxf(v, 0.0f);
    OUT[t] = v;
}

// out[i] = b2 + sum_k T[i,k] * W2[k]
__global__ void k_fc2(const float* __restrict__ T, const float* __restrict__ W2,
                      const float* __restrict__ b2, float* __restrict__ out,
                      int N, int K) {
    int i = blockIdx.x * blockDim.x + threadIdx.x;
    if (i >= N) return;
    const float* tr = T + (long long)i * K;
    float acc = b2[0];
#pragma unroll 4
    for (int k = 0; k < K; ++k) acc += tr[k] * W2[k];
    out[i] = acc;
}

// ---------------- host ----------------

static inline size_t align256(size_t x) { return (x + 255) & ~(size_t)255; }

extern "C" void kernel_launch(void* const* d_in, const int* in_sizes, int n_in,
                              void* d_out, int out_size, void* d_ws, size_t ws_size,
                              hipStream_t stream) {
    const int F_IN = 32;
    const int N = in_sizes[0] / F_IN;   // 50000
    const int E = in_sizes[2];          // 400000

    const float* x    = (const float*)d_in[0];
    const int*   ei   = (const int*)d_in[1];
    const float* ea   = (const float*)d_in[2];
    const int* row = ei;        // edge_index[0]
    const int* col = ei + E;    // edge_index[1]

    // layer params: W,b,g,be for i=1..5 at d_in[3+4*(i-1) ...]
    const float* W[5];  const float* b[5];  const float* g[5];  const float* be[5];
    for (int i = 0; i < 5; ++i) {
        W[i]  = (const float*)d_in[3 + 4 * i + 0];
        b[i]  = (const float*)d_in[3 + 4 * i + 1];
        g[i]  = (const float*)d_in[3 + 4 * i + 2];
        be[i] = (const float*)d_in[3 + 4 * i + 3];
    }
    const float* fcW1 = (const float*)d_in[23];
    const float* fcb1 = (const float*)d_in[24];
    const float* fcW2 = (const float*)d_in[25];
    const float* fcb2 = (const float*)d_in[26];

    // workspace layout
    char* ws = (char*)d_ws;
    size_t off = 0;
    const size_t bufBytes = (size_t)N * 256 * sizeof(float);
    float* BA   = (float*)(ws + off); off += align256(bufBytes);
    float* BB   = (float*)(ws + off); off += align256(bufBytes);
    float* deg  = (float*)(ws + off); off += align256((size_t)N * sizeof(float));
    float* dinv = (float*)(ws + off); off += align256((size_t)N * sizeof(float));
    float* nrm  = (float*)(ws + off); off += align256((size_t)E * sizeof(float));
    float* sums = (float*)(ws + off); off += align256(256 * sizeof(float));
    float* sumsq= (float*)(ws + off); off += align256(256 * sizeof(float));
    (void)ws_size;

    const int BS = 256;
    auto grid1 = [&](long long total) { return (int)((total + BS - 1) / BS); };

    // --- degree / norm precompute ---
    hipMemsetAsync(deg, 0, (size_t)N * sizeof(float), stream);
    k_deg<<<grid1(E), BS, 0, stream>>>(col, ea, deg, E);
    k_dinv<<<grid1(N), BS, 0, stream>>>(deg, dinv, N);
    k_norm<<<grid1(E), BS, 0, stream>>>(row, col, ea, dinv, nrm, E);

    // --- GCN layer helper ---
    // X: input (N x K); P: scratch for Hpre (N x M); A: AGG buffer (N x M), may alias X's storage;
    // OUT: output (N x M), may alias P.
    auto layer = [&](const float* X, float* P, float* A, float* OUT,
                     const float* Wl, const float* bl, const float* gl, const float* bel,
                     int K, int M, int reluBefore, int reluAfter) {
        int nm = N * M;
        k_gemm<<<grid1(nm), BS, 0, stream>>>(X, Wl, nullptr, P, N, K, M, 0);
        hipMemsetAsync(A, 0, (size_t)nm * sizeof(float), stream);
        k_scatter<<<grid1((long long)E * M), BS, 0, stream>>>(row, col, nrm, P, A, E, M);
        k_finish<<<grid1(nm), BS, 0, stream>>>(A, P, dinv, bl, N, M, reluBefore);
        hipMemsetAsync(sums, 0, M * sizeof(float), stream);
        hipMemsetAsync(sumsq, 0, M * sizeof(float), stream);
        k_colsum<<<256, BS, 0, stream>>>(A, sums, sumsq, N, M);
        k_bn<<<grid1(nm), BS, 0, stream>>>(A, sums, sumsq, gl, bel, OUT, N, M, reluAfter);
    };

    // dims: 32 -> 32 -> 64 -> 128 -> 128 -> 256
    layer(x,  BA, BB, BA, W[0], b[0], g[0], be[0], 32,  32,  1, 0);  // L1: out in BA
    layer(BA, BB, BA, BB, W[1], b[1], g[1], be[1], 32,  64,  1, 0);  // L2: out in BB
    layer(BB, BA, BB, BA, W[2], b[2], g[2], be[2], 64,  128, 1, 0);  // L3: out in BA
    layer(BA, BB, BA, BB, W[3], b[3], g[3], be[3], 128, 128, 0, 1);  // L4: out in BB
    layer(BB, BA, BB, BA, W[4], b[4], g[4], be[4], 128, 256, 0, 1);  // L5: out in BA

    // FC1: (N x 256) @ (256 x 128) + b, ReLU -> BB
    k_gemm<<<grid1((long long)N * 128), BS, 0, stream>>>(BA, fcW1, fcb1, BB, N, 256, 128, 1);
    // FC2: (N x 128) @ (128 x 1) + b -> out
    k_fc2<<<grid1(N), BS, 0, stream>>>(BB, fcW2, fcb2, (float*)d_out, N, 128);
}

// Round 6
// 1129.396 us; speedup vs baseline: 2.1145x; 2.1145x over previous
//
#include <hip/hip_runtime.h>

#define EPS 1e-5f

// ---------------- graph preprocessing ----------------

// counts[col[e]]++ (int) and deg[col[e]] += w[e] (float)
__global__ void k_cnt(const int* __restrict__ col, const float* __restrict__ w,
                      int* __restrict__ counts, float* __restrict__ deg, int E) {
    int e = blockIdx.x * blockDim.x + threadIdx.x;
    if (e < E) {
        int c = col[e];
        atomicAdd(&counts[c], 1);
        atomicAdd(&deg[c], w[e]);
    }
}

__global__ void k_dinv(const float* __restrict__ deg, float* __restrict__ dinv, int N) {
    int i = blockIdx.x * blockDim.x + threadIdx.x;
    if (i < N) dinv[i] = rsqrtf(deg[i] + 1.0f);   // + self-loop weight 1, always > 0
}

// exclusive scan of counts -> starts (single block, 1024 threads)
__global__ __launch_bounds__(1024) void k_scan(const int* __restrict__ counts,
                                               int* __restrict__ starts, int N) {
    __shared__ int part[1024];
    int tid = threadIdx.x;
    int chunk = (N + 1023) / 1024;
    int i0 = tid * chunk, i1 = min(N, i0 + chunk);
    int s = 0;
    for (int i = i0; i < i1; ++i) s += counts[i];
    part[tid] = s;
    __syncthreads();
    for (int d = 1; d < 1024; d <<= 1) {
        int v = (tid >= d) ? part[tid - d] : 0;
        __syncthreads();
        part[tid] += v;
        __syncthreads();
    }
    int excl = (tid == 0) ? 0 : part[tid - 1];
    for (int i = i0; i < i1; ++i) { starts[i] = excl; excl += counts[i]; }
}

// place each edge at its CSR slot; permute row index + fused norm into CSR order
__global__ void k_fill(const int* __restrict__ row, const int* __restrict__ col,
                       const float* __restrict__ w, const float* __restrict__ dinv,
                       const int* __restrict__ starts, int* __restrict__ cursor,
                       int* __restrict__ row_s, float* __restrict__ nrm_s, int E) {
    int e = blockIdx.x * blockDim.x + threadIdx.x;
    if (e >= E) return;
    int c = col[e];
    int r = row[e];
    int j = starts[c] + atomicAdd(&cursor[c], 1);
    row_s[j] = r;
    nrm_s[j] = dinv[r] * w[e] * dinv[c];
}

// ---------------- GEMM ----------------

// Tiled GEMM: Y = maybe_relu(X @ W + bias). BM=BN=64, TK=32, 256 thr, 4x4 micro.
// K, M multiples of 32 (true for all layers). N bounds-checked.
__global__ __launch_bounds__(256) void k_gemm_t(
        const float* __restrict__ X, const float* __restrict__ W,
        const float* __restrict__ bias, float* __restrict__ Y,
        int N, int K, int M, int applyRelu)
{
    __shared__ float Xs[64][36];   // 64 rows x TK(32), padded to 36
    __shared__ float Ws[32][64];   // TK x 64 cols

    const int tid = threadIdx.x;
    const int tr = tid >> 4;       // 0..15
    const int tc = tid & 15;       // 0..15
    const int brow = blockIdx.x * 64;
    const int bcol = blockIdx.y * 64;

    float acc[4][4] = {};

    for (int k0 = 0; k0 < K; k0 += 32) {
#pragma unroll
        for (int v = 0; v < 2; ++v) {
            int f = (tid * 2 + v) * 4;
            int r = f >> 5;
            int c = f & 31;
            int gr = brow + r;
            float4 val = make_float4(0.f, 0.f, 0.f, 0.f);
            if (gr < N) val = *(const float4*)(X + (long long)gr * K + k0 + c);
            *(float4*)&Xs[r][c] = val;
        }
#pragma unroll
        for (int v = 0; v < 2; ++v) {
            int f = (tid * 2 + v) * 4;
            int r = f >> 6;
            int c = f & 63;
            int gc = bcol + c;
            float4 val = make_float4(0.f, 0.f, 0.f, 0.f);
            if (gc < M) val = *(const float4*)(W + (long long)(k0 + r) * M + gc);
            *(float4*)&Ws[r][c] = val;
        }
        __syncthreads();

#pragma unroll
        for (int kq = 0; kq < 8; ++kq) {
            float4 a[4], b[4];
#pragma unroll
            for (int ii = 0; ii < 4; ++ii)
                a[ii] = *(const float4*)&Xs[tr * 4 + ii][kq * 4];
#pragma unroll
            for (int kk = 0; kk < 4; ++kk)
                b[kk] = *(const float4*)&Ws[kq * 4 + kk][tc * 4];
#pragma unroll
            for (int kk = 0; kk < 4; ++kk) {
#pragma unroll
                for (int ii = 0; ii < 4; ++ii) {
                    float av = ((const float*)&a[ii])[kk];
                    acc[ii][0] += av * b[kk].x;
                    acc[ii][1] += av * b[kk].y;
                    acc[ii][2] += av * b[kk].z;
                    acc[ii][3] += av * b[kk].w;
                }
            }
        }
        __syncthreads();
    }

    int gc = bcol + tc * 4;
    if (gc < M) {
#pragma unroll
        for (int ii = 0; ii < 4; ++ii) {
            int gr = brow + tr * 4 + ii;
            if (gr >= N) continue;
            float4 o = make_float4(acc[ii][0], acc[ii][1], acc[ii][2], acc[ii][3]);
            if (bias) {
                o.x += bias[gc]; o.y += bias[gc + 1]; o.z += bias[gc + 2]; o.w += bias[gc + 3];
            }
            if (applyRelu) {
                o.x = fmaxf(o.x, 0.f); o.y = fmaxf(o.y, 0.f);
                o.z = fmaxf(o.z, 0.f); o.w = fmaxf(o.w, 0.f);
            }
            *(float4*)(Y + (long long)gr * M + gc) = o;
        }
    }
}

// ---------------- aggregation (CSR gather, fused self-loop + bias + preBN relu) ----------------

// OUT[i,f] = maybe_relu( sum_{j in CSR(i)} nrm_s[j]*H[row_s[j],f] + dinv[i]^2*H[i,f] + b[f] )
__global__ __launch_bounds__(256) void k_gather(
        const int* __restrict__ starts, const int* __restrict__ counts,
        const int* __restrict__ row_s, const float* __restrict__ nrm_s,
        const float* __restrict__ H, const float* __restrict__ dinv,
        const float* __restrict__ bias, float* __restrict__ OUT,
        int N, int M, int applyRelu)
{
    int t = threadIdx.x;
    int npb = 256 / M;                 // nodes per block (M in {32,64,128,256})
    int ln = t / M;
    int f = t - ln * M;
    int i = blockIdx.x * npb + ln;
    if (i >= N) return;
    int s0 = starts[i];
    int cnt = counts[i];
    float acc = 0.f;
    for (int j = s0; j < s0 + cnt; ++j) {
        acc += nrm_s[j] * H[(long long)row_s[j] * M + f];
    }
    float di = dinv[i];
    float v = acc + di * di * H[(long long)i * M + f] + bias[f];
    if (applyRelu) v = fmaxf(v, 0.f);
    OUT[(long long)i * M + f] = v;
}

// ---------------- BN ----------------

__global__ void k_colsum(const float* __restrict__ Y, float* __restrict__ sums,
                         float* __restrict__ sumsq, int N, int M) {
    int f = threadIdx.x & (M - 1);
    int rsub = threadIdx.x / M;
    int R = blockDim.x / M;
    int rowsPerBlock = (N + gridDim.x - 1) / gridDim.x;
    int r0 = blockIdx.x * rowsPerBlock;
    int r1 = min(N, r0 + rowsPerBlock);
    float s = 0.0f, s2 = 0.0f;
    for (int i = r0 + rsub; i < r1; i += R) {
        float v = Y[(long long)i * M + f];
        s += v;
        s2 += v * v;
    }
    atomicAdd(&sums[f], s);
    atomicAdd(&sumsq[f], s2);
}

__global__ void k_bn4(const float* __restrict__ Y, const float* __restrict__ sums,
                      const float* __restrict__ sumsq, const float* __restrict__ g,
                      const float* __restrict__ be, float* __restrict__ OUT,
                      int N, int M, int reluAfter) {
    int t = blockIdx.x * blockDim.x + threadIdx.x;
    int total = (N * M) >> 2;
    if (t >= total) return;
    int f4 = t << 2;
    int i = f4 / M;
    int f = f4 - i * M;
    float invN = 1.0f / (float)N;
    float4 y = *(const float4*)(Y + f4);
    float4 o;
#pragma unroll
    for (int j = 0; j < 4; ++j) {
        float mean = sums[f + j] * invN;
        float var = sumsq[f + j] * invN - mean * mean;
        float v = g[f + j] * (((const float*)&y)[j] - mean) * rsqrtf(var + EPS) + be[f + j];
        if (reluAfter) v = fmaxf(v, 0.f);
        ((float*)&o)[j] = v;
    }
    (void)i;
    *(float4*)(OUT + f4) = o;
}

// out[i] = b2 + sum_k T[i,k] * W2[k]
__global__ void k_fc2(const float* __restrict__ T, const float* __restrict__ W2,
                      const float* __restrict__ b2, float* __restrict__ out,
                      int N, int K) {
    int i = blockIdx.x * blockDim.x + threadIdx.x;
    if (i >= N) return;
    const float* tr = T + (long long)i * K;
    float acc = b2[0];
#pragma unroll 4
    for (int k = 0; k < K; ++k) acc += tr[k] * W2[k];
    out[i] = acc;
}

// ---------------- host ----------------

static inline size_t align256(size_t x) { return (x + 255) & ~(size_t)255; }

extern "C" void kernel_launch(void* const* d_in, const int* in_sizes, int n_in,
                              void* d_out, int out_size, void* d_ws, size_t ws_size,
                              hipStream_t stream) {
    const int F_IN = 32;
    const int N = in_sizes[0] / F_IN;   // 50000
    const int E = in_sizes[2];          // 400000

    const float* x    = (const float*)d_in[0];
    const int*   ei   = (const int*)d_in[1];
    const float* ea   = (const float*)d_in[2];
    const int* row = ei;        // edge_index[0]
    const int* col = ei + E;    // edge_index[1]

    const float* W[5];  const float* b[5];  const float* g[5];  const float* be[5];
    for (int i = 0; i < 5; ++i) {
        W[i]  = (const float*)d_in[3 + 4 * i + 0];
        b[i]  = (const float*)d_in[3 + 4 * i + 1];
        g[i]  = (const float*)d_in[3 + 4 * i + 2];
        be[i] = (const float*)d_in[3 + 4 * i + 3];
    }
    const float* fcW1 = (const float*)d_in[23];
    const float* fcb1 = (const float*)d_in[24];
    const float* fcW2 = (const float*)d_in[25];
    const float* fcb2 = (const float*)d_in[26];

    // workspace layout
    char* ws = (char*)d_ws;
    size_t off = 0;
    const size_t bufBytes = (size_t)N * 256 * sizeof(float);
    float* BA    = (float*)(ws + off); off += align256(bufBytes);
    float* BB    = (float*)(ws + off); off += align256(bufBytes);
    float* deg   = (float*)(ws + off); off += align256((size_t)N * sizeof(float));
    float* dinv  = (float*)(ws + off); off += align256((size_t)N * sizeof(float));
    int*   counts= (int*)  (ws + off); off += align256((size_t)N * sizeof(int));
    int*   starts= (int*)  (ws + off); off += align256((size_t)N * sizeof(int));
    int*   cursor= (int*)  (ws + off); off += align256((size_t)N * sizeof(int));
    int*   row_s = (int*)  (ws + off); off += align256((size_t)E * sizeof(int));
    float* nrm_s = (float*)(ws + off); off += align256((size_t)E * sizeof(float));
    float* sums  = (float*)(ws + off); off += align256(256 * sizeof(float));
    float* sumsq = (float*)(ws + off); off += align256(256 * sizeof(float));
    (void)ws_size;

    const int BS = 256;
    auto grid1 = [&](long long total) { return (int)((total + BS - 1) / BS); };

    // --- CSR build (once per call, reused by all 5 layers) ---
    hipMemsetAsync(deg, 0, (size_t)N * sizeof(float), stream);
    hipMemsetAsync(counts, 0, (size_t)N * sizeof(int), stream);
    hipMemsetAsync(cursor, 0, (size_t)N * sizeof(int), stream);
    k_cnt<<<grid1(E), BS, 0, stream>>>(col, ea, counts, deg, E);
    k_dinv<<<grid1(N), BS, 0, stream>>>(deg, dinv, N);
    k_scan<<<1, 1024, 0, stream>>>(counts, starts, N);
    k_fill<<<grid1(E), BS, 0, stream>>>(row, col, ea, dinv, starts, cursor, row_s, nrm_s, E);

    auto gemm = [&](const float* X, const float* Wm, const float* bias, float* Y,
                    int K, int M, int relu) {
        dim3 grid((N + 63) / 64, (M + 63) / 64);
        k_gemm_t<<<grid, 256, 0, stream>>>(X, Wm, bias, Y, N, K, M, relu);
    };

    // --- GCN layer: gemm -> gather(+selfloop+bias+preBN relu) -> colsum -> bn ---
    auto layer = [&](const float* X, float* P, float* A, float* OUT,
                     const float* Wl, const float* bl, const float* gl, const float* bel,
                     int K, int M, int reluBefore, int reluAfter) {
        int nm = N * M;
        gemm(X, Wl, nullptr, P, K, M, 0);
        int npb = 256 / M;
        k_gather<<<(N + npb - 1) / npb, 256, 0, stream>>>(
            starts, counts, row_s, nrm_s, P, dinv, bl, A, N, M, reluBefore);
        hipMemsetAsync(sums, 0, M * sizeof(float), stream);
        hipMemsetAsync(sumsq, 0, M * sizeof(float), stream);
        k_colsum<<<256, BS, 0, stream>>>(A, sums, sumsq, N, M);
        k_bn4<<<grid1(nm / 4), BS, 0, stream>>>(A, sums, sumsq, gl, bel, OUT, N, M, reluAfter);
    };

    // dims: 32 -> 32 -> 64 -> 128 -> 128 -> 256
    layer(x,  BA, BB, BA, W[0], b[0], g[0], be[0], 32,  32,  1, 0);  // L1: out in BA
    layer(BA, BB, BA, BB, W[1], b[1], g[1], be[1], 32,  64,  1, 0);  // L2: out in BB
    layer(BB, BA, BB, BA, W[2], b[2], g[2], be[2], 64,  128, 1, 0);  // L3: out in BA
    layer(BA, BB, BA, BB, W[3], b[3], g[3], be[3], 128, 128, 0, 1);  // L4: out in BB
    layer(BB, BA, BB, BA, W[4], b[4], g[4], be[4], 128, 256, 0, 1);  // L5: out in BA

    // FC1: (N x 256) @ (256 x 128) + b, ReLU -> BB
    gemm(BA, fcW1, fcb1, BB, 256, 128, 1);
    // FC2: (N x 128) @ (128 x 1) + b -> out
    k_fc2<<<grid1(N), BS, 0, stream>>>(BB, fcW2, fcb2, (float*)d_out, N, 128);
}

// Round 9
// 709.366 us; speedup vs baseline: 3.3666x; 1.5921x over previous
//
#include <hip/hip_runtime.h>

#define EPS 1e-5f

// ---------------- graph preprocessing ----------------

// counts[col[e]]++ (int) and deg[col[e]] += w[e] (float)
__global__ void k_cnt(const int* __restrict__ col, const float* __restrict__ w,
                      int* __restrict__ counts, float* __restrict__ deg, int E) {
    int e = blockIdx.x * blockDim.x + threadIdx.x;
    if (e < E) {
        int c = col[e];
        atomicAdd(&counts[c], 1);
        atomicAdd(&deg[c], w[e]);
    }
}

__global__ void k_dinv(const float* __restrict__ deg, float* __restrict__ dinv, int N) {
    int i = blockIdx.x * blockDim.x + threadIdx.x;
    if (i < N) dinv[i] = rsqrtf(deg[i] + 1.0f);   // + self-loop weight 1, always > 0
}

// exclusive scan of counts -> starts (single block, 1024 threads)
__global__ __launch_bounds__(1024) void k_scan(const int* __restrict__ counts,
                                               int* __restrict__ starts, int N) {
    __shared__ int part[1024];
    int tid = threadIdx.x;
    int chunk = (N + 1023) / 1024;
    int i0 = tid * chunk, i1 = min(N, i0 + chunk);
    int s = 0;
    for (int i = i0; i < i1; ++i) s += counts[i];
    part[tid] = s;
    __syncthreads();
    for (int d = 1; d < 1024; d <<= 1) {
        int v = (tid >= d) ? part[tid - d] : 0;
        __syncthreads();
        part[tid] += v;
        __syncthreads();
    }
    int excl = (tid == 0) ? 0 : part[tid - 1];
    for (int i = i0; i < i1; ++i) { starts[i] = excl; excl += counts[i]; }
}

// place each edge at its CSR slot; permute row index + fused norm into CSR order
__global__ void k_fill(const int* __restrict__ row, const int* __restrict__ col,
                       const float* __restrict__ w, const float* __restrict__ dinv,
                       const int* __restrict__ starts, int* __restrict__ cursor,
                       int* __restrict__ row_s, float* __restrict__ nrm_s, int E) {
    int e = blockIdx.x * blockDim.x + threadIdx.x;
    if (e >= E) return;
    int c = col[e];
    int r = row[e];
    int j = starts[c] + atomicAdd(&cursor[c], 1);
    row_s[j] = r;
    nrm_s[j] = dinv[r] * w[e] * dinv[c];
}

// ---------------- aggregation (CSR gather on the INPUT side, float4) ----------------
// OUT[i, f4] = sum_j nrm_s[j]*X[row_s[j], f4] + dinv[i]^2 * X[i, f4]   (float4 lanes)
__global__ __launch_bounds__(256) void k_gather4(
        const int* __restrict__ starts, const int* __restrict__ counts,
        const int* __restrict__ row_s, const float* __restrict__ nrm_s,
        const float* __restrict__ X, const float* __restrict__ dinv,
        float* __restrict__ OUT, int N, int k4shift)
{
    int t = blockIdx.x * blockDim.x + threadIdx.x;
    int K4 = 1 << k4shift;                // K/4 : 8,16,32
    if (t >= (N << k4shift)) return;
    int i = t >> k4shift;
    int f4 = t & (K4 - 1);
    const float4* X4 = (const float4*)X;
    int s0 = starts[i];
    int cnt = counts[i];
    float4 acc = make_float4(0.f, 0.f, 0.f, 0.f);
    for (int j = s0; j < s0 + cnt; ++j) {
        float w = nrm_s[j];
        float4 h = X4[(long long)row_s[j] * K4 + f4];
        acc.x += w * h.x; acc.y += w * h.y; acc.z += w * h.z; acc.w += w * h.w;
    }
    float di = dinv[i];
    float dd = di * di;
    float4 hs = X4[(long long)i * K4 + f4];
    acc.x += dd * hs.x; acc.y += dd * hs.y; acc.z += dd * hs.z; acc.w += dd * hs.w;
    ((float4*)OUT)[t] = acc;
}

// ---------------- GEMM (+bias, +optional relu, +optional fused BN colsum) ----------------
// Y = maybe_relu(X @ W + bias); if sums!=null, also atomically accumulate per-column
// sum and sum-of-squares of the WRITTEN values (BN statistics).
__global__ __launch_bounds__(256) void k_gemm_t(
        const float* __restrict__ X, const float* __restrict__ W,
        const float* __restrict__ bias, float* __restrict__ Y,
        int N, int K, int M, int applyRelu,
        float* __restrict__ sums, float* __restrict__ sumsq)
{
    __shared__ float Xs[64][36];   // 64 rows x TK(32), padded to 36
    __shared__ float Ws[32][64];   // TK x 64 cols
    __shared__ float red[16][64];  // colsum reduction scratch

    const int tid = threadIdx.x;
    const int tr = tid >> 4;       // 0..15
    const int tc = tid & 15;       // 0..15
    const int brow = blockIdx.x * 64;
    const int bcol = blockIdx.y * 64;

    float acc[4][4] = {};

    for (int k0 = 0; k0 < K; k0 += 32) {
#pragma unroll
        for (int v = 0; v < 2; ++v) {
            int f = (tid * 2 + v) * 4;
            int r = f >> 5;
            int c = f & 31;
            int gr = brow + r;
            float4 val = make_float4(0.f, 0.f, 0.f, 0.f);
            if (gr < N) val = *(const float4*)(X + (long long)gr * K + k0 + c);
            *(float4*)&Xs[r][c] = val;
        }
#pragma unroll
        for (int v = 0; v < 2; ++v) {
            int f = (tid * 2 + v) * 4;
            int r = f >> 6;
            int c = f & 63;
            int gc = bcol + c;
            float4 val = make_float4(0.f, 0.f, 0.f, 0.f);
            if (gc < M) val = *(const float4*)(W + (long long)(k0 + r) * M + gc);
            *(float4*)&Ws[r][c] = val;
        }
        __syncthreads();

#pragma unroll
        for (int kq = 0; kq < 8; ++kq) {
            float4 a[4], b[4];
#pragma unroll
            for (int ii = 0; ii < 4; ++ii)
                a[ii] = *(const float4*)&Xs[tr * 4 + ii][kq * 4];
#pragma unroll
            for (int kk = 0; kk < 4; ++kk)
                b[kk] = *(const float4*)&Ws[kq * 4 + kk][tc * 4];
#pragma unroll
            for (int kk = 0; kk < 4; ++kk) {
#pragma unroll
                for (int ii = 0; ii < 4; ++ii) {
                    float av = ((const float*)&a[ii])[kk];
                    acc[ii][0] += av * b[kk].x;
                    acc[ii][1] += av * b[kk].y;
                    acc[ii][2] += av * b[kk].z;
                    acc[ii][3] += av * b[kk].w;
                }
            }
        }
        __syncthreads();
    }

    const int gc = bcol + tc * 4;
    float4 o[4];
    bool rv[4];
#pragma unroll
    for (int ii = 0; ii < 4; ++ii) {
        int gr = brow + tr * 4 + ii;
        rv[ii] = (gr < N);
        float4 v = make_float4(acc[ii][0], acc[ii][1], acc[ii][2], acc[ii][3]);
        if (gc < M) {
            if (bias) {
                v.x += bias[gc]; v.y += bias[gc + 1]; v.z += bias[gc + 2]; v.w += bias[gc + 3];
            }
            if (applyRelu) {
                v.x = fmaxf(v.x, 0.f); v.y = fmaxf(v.y, 0.f);
                v.z = fmaxf(v.z, 0.f); v.w = fmaxf(v.w, 0.f);
            }
            if (rv[ii]) *(float4*)(Y + (long long)(brow + tr * 4 + ii) * M + gc) = v;
        }
        o[ii] = v;
    }

    if (sums) {
        float4 ps = make_float4(0.f, 0.f, 0.f, 0.f);
        float4 ps2 = make_float4(0.f, 0.f, 0.f, 0.f);
#pragma unroll
        for (int ii = 0; ii < 4; ++ii) {
            if (!rv[ii]) continue;
            ps.x += o[ii].x; ps.y += o[ii].y; ps.z += o[ii].z; ps.w += o[ii].w;
            ps2.x += o[ii].x * o[ii].x; ps2.y += o[ii].y * o[ii].y;
            ps2.z += o[ii].z * o[ii].z; ps2.w += o[ii].w * o[ii].w;
        }
        *(float4*)&red[tr][tc * 4] = ps;
        __syncthreads();
        if (tid < 64) {
            float s = 0.f;
#pragma unroll
            for (int r = 0; r < 16; ++r) s += red[r][tid];
            if (bcol + tid < M) atomicAdd(&sums[bcol + tid], s);
        }
        __syncthreads();
        *(float4*)&red[tr][tc * 4] = ps2;
        __syncthreads();
        if (tid < 64) {
            float s = 0.f;
#pragma unroll
            for (int r = 0; r < 16; ++r) s += red[r][tid];
            if (bcol + tid < M) atomicAdd(&sumsq[bcol + tid], s);
        }
    }
}

// ---------------- BN (in-place capable) ----------------

__global__ void k_bn4(const float* __restrict__ Y, const float* __restrict__ sums,
                      const float* __restrict__ sumsq, const float* __restrict__ g,
                      const float* __restrict__ be, float* __restrict__ OUT,
                      int N, int M, int reluAfter) {
    int t = blockIdx.x * blockDim.x + threadIdx.x;
    int total = (N * M) >> 2;
    if (t >= total) return;
    int f4 = t << 2;
    int i = f4 / M;
    int f = f4 - i * M;
    float invN = 1.0f / (float)N;
    float4 y = *(const float4*)(Y + f4);
    float4 o;
#pragma unroll
    for (int j = 0; j < 4; ++j) {
        float mean = sums[f + j] * invN;
        float var = sumsq[f + j] * invN - mean * mean;
        float v = g[f + j] * (((const float*)&y)[j] - mean) * rsqrtf(var + EPS) + be[f + j];
        if (reluAfter) v = fmaxf(v, 0.f);
        ((float*)&o)[j] = v;
    }
    (void)i;
    *(float4*)(OUT + f4) = o;
}

// out[i] = b2 + sum_k T[i,k] * W2[k]
__global__ void k_fc2(const float* __restrict__ T, const float* __restrict__ W2,
                      const float* __restrict__ b2, float* __restrict__ out,
                      int N, int K) {
    int i = blockIdx.x * blockDim.x + threadIdx.x;
    if (i >= N) return;
    const float* tr = T + (long long)i * K;
    float acc = b2[0];
#pragma unroll 4
    for (int k = 0; k < K; ++k) acc += tr[k] * W2[k];
    out[i] = acc;
}

// ---------------- host ----------------

static inline size_t align256(size_t x) { return (x + 255) & ~(size_t)255; }

extern "C" void kernel_launch(void* const* d_in, const int* in_sizes, int n_in,
                              void* d_out, int out_size, void* d_ws, size_t ws_size,
                              hipStream_t stream) {
    const int F_IN = 32;
    const int N = in_sizes[0] / F_IN;   // 50000
    const int E = in_sizes[2];          // 400000

    const float* x    = (const float*)d_in[0];
    const int*   ei   = (const int*)d_in[1];
    const float* ea   = (const float*)d_in[2];
    const int* row = ei;        // edge_index[0]
    const int* col = ei + E;    // edge_index[1]

    const float* W[5];  const float* b[5];  const float* g[5];  const float* be[5];
    for (int i = 0; i < 5; ++i) {
        W[i]  = (const float*)d_in[3 + 4 * i + 0];
        b[i]  = (const float*)d_in[3 + 4 * i + 1];
        g[i]  = (const float*)d_in[3 + 4 * i + 2];
        be[i] = (const float*)d_in[3 + 4 * i + 3];
    }
    const float* fcW1 = (const float*)d_in[23];
    const float* fcb1 = (const float*)d_in[24];
    const float* fcW2 = (const float*)d_in[25];
    const float* fcb2 = (const float*)d_in[26];

    // workspace layout
    char* ws = (char*)d_ws;
    size_t off = 0;
    const size_t bufBytes = (size_t)N * 256 * sizeof(float);
    float* BA    = (float*)(ws + off); off += align256(bufBytes);
    float* BB    = (float*)(ws + off); off += align256(bufBytes);
    float* C     = (float*)(ws + off); off += align256((size_t)N * 128 * sizeof(float));
    float* deg   = (float*)(ws + off); off += align256((size_t)N * sizeof(float));
    float* dinv  = (float*)(ws + off); off += align256((size_t)N * sizeof(float));
    int*   counts= (int*)  (ws + off); off += align256((size_t)N * sizeof(int));
    int*   starts= (int*)  (ws + off); off += align256((size_t)N * sizeof(int));
    int*   cursor= (int*)  (ws + off); off += align256((size_t)N * sizeof(int));
    int*   row_s = (int*)  (ws + off); off += align256((size_t)E * sizeof(int));
    float* nrm_s = (float*)(ws + off); off += align256((size_t)E * sizeof(float));
    float* sums  = (float*)(ws + off); off += align256(256 * sizeof(float));
    float* sumsq = (float*)(ws + off); off += align256(256 * sizeof(float));
    (void)ws_size;

    const int BS = 256;
    auto grid1 = [&](long long total) { return (int)((total + BS - 1) / BS); };

    // --- CSR build (once per call, reused by all 5 layers) ---
    hipMemsetAsync(deg, 0, (size_t)N * sizeof(float), stream);
    hipMemsetAsync(counts, 0, (size_t)N * sizeof(int), stream);
    hipMemsetAsync(cursor, 0, (size_t)N * sizeof(int), stream);
    k_cnt<<<grid1(E), BS, 0, stream>>>(col, ea, counts, deg, E);
    k_dinv<<<grid1(N), BS, 0, stream>>>(deg, dinv, N);
    k_scan<<<1, 1024, 0, stream>>>(counts, starts, N);
    k_fill<<<grid1(E), BS, 0, stream>>>(row, col, ea, dinv, starts, cursor, row_s, nrm_s, E);

    auto gemm = [&](const float* X, const float* Wm, const float* bias, float* Y,
                    int K, int M, int relu, float* s1, float* s2) {
        dim3 grid((N + 63) / 64, (M + 63) / 64);
        k_gemm_t<<<grid, 256, 0, stream>>>(X, Wm, bias, Y, N, K, M, relu, s1, s2);
    };

    // --- GCN layer: gather(X)->C ; gemm(C)+bias+preRelu+colsum -> OUT ; bn in-place ---
    auto layer = [&](const float* X, float* OUT, int K, int M, int l,
                     int reluBefore, int reluAfter) {
        int k4shift = (K == 32) ? 3 : (K == 64) ? 4 : 5;
        k_gather4<<<grid1((long long)N << k4shift), BS, 0, stream>>>(
            starts, counts, row_s, nrm_s, X, dinv, C, N, k4shift);
        hipMemsetAsync(sums, 0, M * sizeof(float), stream);
        hipMemsetAsync(sumsq, 0, M * sizeof(float), stream);
        gemm(C, W[l], b[l], OUT, K, M, reluBefore, sums, sumsq);
        k_bn4<<<grid1((long long)N * M / 4), BS, 0, stream>>>(
            OUT, sums, sumsq, g[l], be[l], OUT, N, M, reluAfter);
    };

    // dims: 32 -> 32 -> 64 -> 128 -> 128 -> 256
    layer(x,  BA, 32,  32,  0, 1, 0);  // L1: out in BA
    layer(BA, BB, 32,  64,  1, 1, 0);  // L2: out in BB
    layer(BB, BA, 64,  128, 2, 1, 0);  // L3: out in BA
    layer(BA, BB, 128, 128, 3, 0, 1);  // L4: out in BB
    layer(BB, BA, 128, 256, 4, 0, 1);  // L5: out in BA

    // FC1: (N x 256) @ (256 x 128) + b, ReLU -> BB (no BN stats)
    gemm(BA, fcW1, fcb1, BB, 256, 128, 1, nullptr, nullptr);
    // FC2: (N x 128) @ (128 x 1) + b -> out
    k_fc2<<<grid1(N), BS, 0, stream>>>(BB, fcW2, fcb2, (float*)d_out, N, 128);
}